// Round 1
// baseline (307.014 us; speedup 1.0000x reference)
//
#include <hip/hip_runtime.h>

#define HW 32768      // H*W per batch = 128*256
#define WIDTH 256

typedef float f32x4 __attribute__((ext_vector_type(4)));
typedef short s16x8 __attribute__((ext_vector_type(8)));

__device__ __forceinline__ unsigned short f2bf(float f){
    unsigned int u = __float_as_uint(f);
    u += 0x7FFFu + ((u >> 16) & 1u);      // round-to-nearest-even
    return (unsigned short)(u >> 16);
}
__device__ __forceinline__ unsigned int pk2(float a, float b){
    return (unsigned int)f2bf(a) | ((unsigned int)f2bf(b) << 16);
}

// ---------------------------------------------------------------------------
// K1: fmap = W(128x128) @ feat + b, normalize over channels, write bf16
//     TRANSPOSED: fmapN[b][pixel][c]  (so corr can load c-contiguous frags)
// Block: 256 thr = 4 waves; tile = 128 outputs x 256 pixels; K chunked by 32.
// A (=W) frags from LDS b128 reads; B (=feat) frags via 8 u16 LDS reads.
// ---------------------------------------------------------------------------
__global__ __launch_bounds__(256, 2) void k_fmap(
    const float* __restrict__ fl, const float* __restrict__ fr,
    const float* __restrict__ W1, const float* __restrict__ W2,
    const float* __restrict__ b1, const float* __restrict__ b2,
    unsigned short* __restrict__ f1N, unsigned short* __restrict__ f2N)
{
    const int z = blockIdx.z;
    const float* feat = z ? fr : fl;
    const float* Wm   = z ? W2 : W1;
    const float* bias = z ? b2 : b1;
    unsigned short* out = z ? f2N : f1N;

    const int b    = blockIdx.y;
    const int pxb  = blockIdx.x * 256;
    const int tid  = threadIdx.x;
    const int wv   = tid >> 6;
    const int lane = tid & 63;
    const int quad = lane >> 4;
    const int l15  = lane & 15;

    __shared__ unsigned short Xs[32][260];   // 32 c-rows x 256 px (+pad)
    __shared__ unsigned short Ws[128][40];   // 128 o-rows x 32 c  (+pad)

    f32x4 acc[8][4];
    #pragma unroll
    for (int m = 0; m < 8; ++m)
        #pragma unroll
        for (int nt = 0; nt < 4; ++nt)
            acc[m][nt] = (f32x4){0.f,0.f,0.f,0.f};

    const float* featB = feat + (size_t)b * 128 * HW + pxb;

    for (int kk = 0; kk < 4; ++kk){
        const int kc0 = kk * 32;
        __syncthreads();
        // stage feat chunk: 32 rows (c) x 256 cols (px), fp32 -> bf16
        #pragma unroll
        for (int i = 0; i < 8; ++i){
            int u   = tid + i * 256;          // 0..2047
            int row = u >> 6;
            int cp  = (u & 63) << 2;
            f32x4 v = *(const f32x4*)(featB + (size_t)(kc0 + row) * HW + cp);
            uint2 pk; pk.x = pk2(v[0], v[1]); pk.y = pk2(v[2], v[3]);
            *(uint2*)&Xs[row][cp] = pk;
        }
        // stage W chunk: 128 rows (o) x 32 cols (c)
        #pragma unroll
        for (int i = 0; i < 4; ++i){
            int u   = tid + i * 256;          // 0..1023
            int row = u >> 3;
            int cp  = (u & 7) << 2;
            f32x4 v = *(const f32x4*)(Wm + row * 128 + kc0 + cp);
            uint2 pk; pk.x = pk2(v[0], v[1]); pk.y = pk2(v[2], v[3]);
            *(uint2*)&Ws[row][cp] = pk;
        }
        __syncthreads();

        s16x8 af[8];
        #pragma unroll
        for (int m = 0; m < 8; ++m)
            af[m] = *(const s16x8*)&Ws[m * 16 + l15][quad * 8];

        #pragma unroll
        for (int nt = 0; nt < 4; ++nt){
            const int px = wv * 64 + nt * 16 + l15;
            s16x8 bf;
            #pragma unroll
            for (int j = 0; j < 8; ++j)
                bf[j] = (short)Xs[quad * 8 + j][px];
            #pragma unroll
            for (int m = 0; m < 8; ++m)
                acc[m][nt] = __builtin_amdgcn_mfma_f32_16x16x32_bf16(af[m], bf, acc[m][nt], 0, 0, 0);
        }
    }

    // epilogue: +bias, L2-normalize per pixel (column), write bf16 transposed
    #pragma unroll
    for (int nt = 0; nt < 4; ++nt){
        const int px = wv * 64 + nt * 16 + l15;
        #pragma unroll
        for (int m = 0; m < 8; ++m){
            f32x4 bv = *(const f32x4*)(bias + m * 16 + quad * 4);
            acc[m][nt] += bv;
        }
        float n2 = 0.f;
        #pragma unroll
        for (int m = 0; m < 8; ++m)
            #pragma unroll
            for (int r = 0; r < 4; ++r)
                n2 += acc[m][nt][r] * acc[m][nt][r];
        n2 += __shfl_xor(n2, 16, 64);
        n2 += __shfl_xor(n2, 32, 64);
        const float scale = 1.f / (sqrtf(n2) + 1e-8f);
        unsigned short* orow = out + ((size_t)b * HW + pxb + px) * 128;
        #pragma unroll
        for (int m = 0; m < 8; ++m){
            uint2 pk;
            pk.x = pk2(acc[m][nt][0] * scale, acc[m][nt][1] * scale);
            pk.y = pk2(acc[m][nt][2] * scale, acc[m][nt][3] * scale);
            *(uint2*)(orow + m * 16 + quad * 4) = pk;
        }
    }
}

// ---------------------------------------------------------------------------
// K2: correlation volume via MFMA + diagonal gather.
// Per wave: 16-px strip. G[16px][64s] = f1n_strip^T (16x128) @ f2n_slab (128x64)
// where s covers shifts; out[d][x0+px] = G[px][px+48-d]. OOB shifts -> zero frag.
// ---------------------------------------------------------------------------
__global__ __launch_bounds__(256, 4) void k_corr(
    const unsigned short* __restrict__ f1N,
    const unsigned short* __restrict__ f2N,
    float* __restrict__ ic)
{
    const int tid  = threadIdx.x;
    const int wv   = tid >> 6;
    const int lane = tid & 63;
    const int quad = lane >> 4;
    const int l15  = lane & 15;

    const int strip = blockIdx.x * 4 + wv;    // 0..8191
    const int b   = strip >> 11;
    const int rem = strip & 2047;
    const int h   = rem >> 4;
    const int x0  = (rem & 15) << 4;

    const size_t rowbase = (size_t)b * HW + (size_t)h * WIDTH;

    const unsigned short* arow = f1N + (rowbase + x0 + l15) * 128;
    s16x8 af[4];
    #pragma unroll
    for (int kk = 0; kk < 4; ++kk)
        af[kk] = *(const s16x8*)(arow + kk * 32 + quad * 8);

    f32x4 acc[4];
    #pragma unroll
    for (int nt = 0; nt < 4; ++nt) acc[nt] = (f32x4){0.f,0.f,0.f,0.f};

    #pragma unroll
    for (int nt = 0; nt < 4; ++nt){
        const int s = x0 + nt * 16 + l15 - 24;
        const bool valid = (s >= 0) && (s < WIDTH);
        const unsigned short* brow = f2N + (rowbase + s) * 128;
        #pragma unroll
        for (int kk = 0; kk < 4; ++kk){
            s16x8 bf = (s16x8){0,0,0,0,0,0,0,0};
            if (valid) bf = *(const s16x8*)(brow + kk * 32 + quad * 8);
            acc[nt] = __builtin_amdgcn_mfma_f32_16x16x32_bf16(af[kk], bf, acc[nt], 0, 0, 0);
        }
    }

    __shared__ float G[4][16][68];
    #pragma unroll
    for (int nt = 0; nt < 4; ++nt)
        #pragma unroll
        for (int r = 0; r < 4; ++r)
            G[wv][quad * 4 + r][nt * 16 + l15] = acc[nt][r];
    __syncthreads();

    float* obase = ic + (size_t)b * 49 * HW + (size_t)h * WIDTH + x0;
    #pragma unroll
    for (int i = 0; i < 13; ++i){
        int dd = quad + i * 4;
        if (dd < 49){
            float v = G[wv][l15][l15 + 48 - dd];
            obase[(size_t)dd * HW + l15] = v;
        }
    }
}

// ---------------------------------------------------------------------------
// K3: collapse geo path: M[s][i][k] = sum_o W_sel[s][i*96+o]*W_geo[o][k];
//     c0[s] = b_sel[s] + sum_{i,o} W_sel[s][i*96+o]*b_geo[o]
// ---------------------------------------------------------------------------
__global__ void k_prep(const float* __restrict__ Wsel, const float* __restrict__ bsel,
                       const float* __restrict__ Wgeo, const float* __restrict__ bgeo,
                       float* __restrict__ M, float* __restrict__ c0)
{
    int u = threadIdx.x;
    if (u < 441){
        int s = u / 147; int r = u % 147; int i = r / 49; int k = r % 49;
        float acc = 0.f;
        for (int o = 0; o < 96; ++o)
            acc += Wsel[s * 288 + i * 96 + o] * Wgeo[o * 49 + k];
        M[u] = acc;
    } else if (u < 444){
        int s = u - 441;
        float acc = bsel[s];
        for (int i = 0; i < 3; ++i)
            for (int o = 0; o < 96; ++o)
                acc += Wsel[s * 288 + i * 96 + o] * bgeo[o];
        c0[s] = acc;
    }
}

// ---------------------------------------------------------------------------
// K4: logits via collapsed M, softmax -> w, final = ic + w·cv
// ---------------------------------------------------------------------------
__global__ __launch_bounds__(256, 4) void k_sel(
    const float* __restrict__ cv0, const float* __restrict__ cv1, const float* __restrict__ cv2,
    const float* __restrict__ M, const float* __restrict__ c0,
    const float* __restrict__ ic,
    float* __restrict__ finalO, float* __restrict__ wO)
{
    __shared__ float Ms[441];
    __shared__ float c0s[3];
    const int tid = threadIdx.x;
    for (int i = tid; i < 441; i += 256) Ms[i] = M[i];
    if (tid < 3) c0s[tid] = c0[tid];
    __syncthreads();

    const int gid = blockIdx.x * 256 + tid;   // 0..131071
    const int b = gid >> 15;
    const int p = gid & 32767;
    const size_t base = (size_t)b * 49 * HW + p;

    float lg0 = c0s[0], lg1 = c0s[1], lg2 = c0s[2];
    for (int k = 0; k < 49; ++k){
        size_t o = base + (size_t)k * HW;
        float v0 = cv0[o], v1 = cv1[o], v2 = cv2[o];
        lg0 += Ms[k]       * v0 + Ms[49  + k] * v1 + Ms[98  + k] * v2;
        lg1 += Ms[147 + k] * v0 + Ms[196 + k] * v1 + Ms[245 + k] * v2;
        lg2 += Ms[294 + k] * v0 + Ms[343 + k] * v1 + Ms[392 + k] * v2;
    }
    float mx = fmaxf(lg0, fmaxf(lg1, lg2));
    float e0 = expf(lg0 - mx), e1 = expf(lg1 - mx), e2 = expf(lg2 - mx);
    float inv = 1.f / (e0 + e1 + e2);
    float w0 = e0 * inv, w1 = e1 * inv, w2 = e2 * inv;

    const size_t wbase = (size_t)b * 3 * HW + p;
    wO[wbase]          = w0;
    wO[wbase + HW]     = w1;
    wO[wbase + 2 * HW] = w2;

    for (int k = 0; k < 49; ++k){
        size_t o = base + (size_t)k * HW;
        finalO[o] = ic[o] + w0 * cv0[o] + w1 * cv1[o] + w2 * cv2[o];
    }
}

// ---------------------------------------------------------------------------
extern "C" void kernel_launch(void* const* d_in, const int* in_sizes, int n_in,
                              void* d_out, int out_size, void* d_ws, size_t ws_size,
                              hipStream_t stream)
{
    const float* feat_l1 = (const float*)d_in[0];
    const float* feat_r1 = (const float*)d_in[1];
    const float* cv0     = (const float*)d_in[2];
    const float* cv1     = (const float*)d_in[3];
    const float* cv2     = (const float*)d_in[4];
    const float* W_f1    = (const float*)d_in[5];
    const float* b_f1    = (const float*)d_in[6];
    const float* W_f2    = (const float*)d_in[7];
    const float* b_f2    = (const float*)d_in[8];
    const float* W_geo   = (const float*)d_in[9];
    const float* b_geo   = (const float*)d_in[10];
    const float* W_sel   = (const float*)d_in[11];
    const float* b_sel   = (const float*)d_in[12];

    float* finalO = (float*)d_out;
    float* icO    = (float*)d_out + 6422528;    // 4*49*128*256
    float* wO     = (float*)d_out + 12845056;   // + another 6422528

    // workspace: two bf16 normalized fmaps (transposed) + tiny M/c0
    unsigned short* f1N = (unsigned short*)d_ws;
    unsigned short* f2N = (unsigned short*)((char*)d_ws + 33554432);
    float* Mbuf  = (float*)((char*)d_ws + 67108864);
    float* c0buf = Mbuf + 441;

    k_prep<<<1, 512, 0, stream>>>(W_sel, b_sel, W_geo, b_geo, Mbuf, c0buf);
    k_fmap<<<dim3(128, 4, 2), 256, 0, stream>>>(feat_l1, feat_r1, W_f1, W_f2, b_f1, b_f2, f1N, f2N);
    k_corr<<<2048, 256, 0, stream>>>(f1N, f2N, icO);
    k_sel<<<512, 256, 0, stream>>>(cv0, cv1, cv2, Mbuf, c0buf, icO, finalO, wO);
}

// Round 3
// 301.726 us; speedup vs baseline: 1.0175x; 1.0175x over previous
//
#include <hip/hip_runtime.h>

#define HW 32768      // H*W per batch = 128*256
#define WIDTH 256

typedef float f32x4 __attribute__((ext_vector_type(4)));
typedef short s16x8 __attribute__((ext_vector_type(8)));

__device__ __forceinline__ unsigned short f2bf(float f){
    unsigned int u = __float_as_uint(f);
    u += 0x7FFFu + ((u >> 16) & 1u);      // round-to-nearest-even
    return (unsigned short)(u >> 16);
}
__device__ __forceinline__ unsigned int pk2(float a, float b){
    return (unsigned int)f2bf(a) | ((unsigned int)f2bf(b) << 16);
}

// ---------------------------------------------------------------------------
// K1: fmap = W(128x128) @ feat + b, L2-normalize per pixel, write bf16
//     TRANSPOSED: fmapN[b][pixel][c].
// No LDS in main loop: feat has no cross-wave reuse (reuse is across the 128
// outputs, all held in one wave's accumulators); W is 64 KB -> L1-resident.
// Fragments loaded straight from global, packed fp32->bf16 in registers.
// Epilogue: LDS transpose so global stores are 16B/lane coalesced.
// ---------------------------------------------------------------------------
__global__ __launch_bounds__(256, 2) void k_fmap(
    const float* __restrict__ fl, const float* __restrict__ fr,
    const float* __restrict__ W1, const float* __restrict__ W2,
    const float* __restrict__ b1, const float* __restrict__ b2,
    unsigned short* __restrict__ f1N, unsigned short* __restrict__ f2N)
{
    const int z = blockIdx.z;
    const float* feat = z ? fr : fl;
    const float* Wm   = z ? W2 : W1;
    const float* bias = z ? b2 : b1;
    unsigned short* out = z ? f2N : f1N;

    const int b    = blockIdx.y;
    const int pxb  = blockIdx.x * 256;
    const int tid  = threadIdx.x;
    const int wv   = tid >> 6;
    const int lane = tid & 63;
    const int quad = lane >> 4;
    const int l15  = lane & 15;

    f32x4 acc[8][4];
    #pragma unroll
    for (int m = 0; m < 8; ++m)
        #pragma unroll
        for (int nt = 0; nt < 4; ++nt)
            acc[m][nt] = (f32x4){0.f,0.f,0.f,0.f};

    const float* featB = feat + (size_t)b * 128 * HW + pxb;

    #pragma unroll
    for (int kk = 0; kk < 4; ++kk){
        const int kc0 = kk * 32;

        // A (=W) frags: A[m'=l15][k=quad*8+j] = W[m*16+l15][kc0+quad*8+j]
        s16x8 af[8];
        #pragma unroll
        for (int m = 0; m < 8; ++m){
            const float* wp = Wm + (m * 16 + l15) * 128 + kc0 + quad * 8;
            f32x4 w0 = *(const f32x4*)wp;
            f32x4 w1 = *(const f32x4*)(wp + 4);
            union { unsigned int u[4]; s16x8 v; } r;
            r.u[0] = pk2(w0[0], w0[1]); r.u[1] = pk2(w0[2], w0[3]);
            r.u[2] = pk2(w1[0], w1[1]); r.u[3] = pk2(w1[2], w1[3]);
            af[m] = r.v;
        }

        #pragma unroll
        for (int nt = 0; nt < 4; ++nt){
            const int px = wv * 64 + nt * 16 + l15;
            // B frag: B[k=quad*8+j][n=l15] = feat[kc0+quad*8+j][px]
            const float* bp = featB + (size_t)(kc0 + quad * 8) * HW + px;
            float x[8];
            #pragma unroll
            for (int j = 0; j < 8; ++j)
                x[j] = bp[(size_t)j * HW];
            union { unsigned int u[4]; s16x8 v; } r;
            r.u[0] = pk2(x[0], x[1]); r.u[1] = pk2(x[2], x[3]);
            r.u[2] = pk2(x[4], x[5]); r.u[3] = pk2(x[6], x[7]);
            const s16x8 bf = r.v;
            #pragma unroll
            for (int m = 0; m < 8; ++m)
                acc[m][nt] = __builtin_amdgcn_mfma_f32_16x16x32_bf16(af[m], bf, acc[m][nt], 0, 0, 0);
        }
    }

    // epilogue: +bias, L2-normalize per pixel, LDS-transpose, coalesced store
    __shared__ unsigned short Ts[64][132];   // row stride 264 B (8B-aligned)

    for (int nt = 0; nt < 4; ++nt){
        __syncthreads();   // Ts reuse across nt passes
        #pragma unroll
        for (int m = 0; m < 8; ++m){
            f32x4 bv = *(const f32x4*)(bias + m * 16 + quad * 4);
            acc[m][nt] += bv;
        }
        float n2 = 0.f;
        #pragma unroll
        for (int m = 0; m < 8; ++m)
            #pragma unroll
            for (int r = 0; r < 4; ++r)
                n2 += acc[m][nt][r] * acc[m][nt][r];
        n2 += __shfl_xor(n2, 16, 64);
        n2 += __shfl_xor(n2, 32, 64);
        const float scale = 1.f / (sqrtf(n2) + 1e-8f);

        unsigned short* trow = &Ts[wv * 16 + l15][0];
        #pragma unroll
        for (int m = 0; m < 8; ++m){
            uint2 pk;
            pk.x = pk2(acc[m][nt][0] * scale, acc[m][nt][1] * scale);
            pk.y = pk2(acc[m][nt][2] * scale, acc[m][nt][3] * scale);
            *(uint2*)(trow + m * 16 + quad * 4) = pk;
        }
        __syncthreads();

        // cooperative coalesced store: thread -> 64 B (32 shorts) of one pixel row
        const int s  = tid >> 2;          // pixel slot 0..63
        const int ch = tid & 3;           // 64-B chunk
        const int wvs = s >> 4, ls = s & 15;
        const int gpx = pxb + wvs * 64 + nt * 16 + ls;
        const unsigned short* src = &Ts[s][ch * 32];
        unsigned short* dst = out + ((size_t)b * HW + gpx) * 128 + ch * 32;
        #pragma unroll
        for (int i = 0; i < 4; ++i){      // 4 x 8 shorts = 32 shorts
            union { struct { uint2 a, c; } p; s16x8 v; } m;
            m.p.a = *(const uint2*)(src + i * 8);
            m.p.c = *(const uint2*)(src + i * 8 + 4);
            *(s16x8*)(dst + i * 8) = m.v;
        }
    }
}

// ---------------------------------------------------------------------------
// K2: correlation volume via MFMA + diagonal gather.
// Per wave: 16-px strip. G[16px][64s] = f1n_strip^T (16x128) @ f2n_slab (128x64)
// where s covers shifts; out[d][x0+px] = G[px][px+48-d]. OOB shifts -> zero frag.
// ---------------------------------------------------------------------------
__global__ __launch_bounds__(256, 4) void k_corr(
    const unsigned short* __restrict__ f1N,
    const unsigned short* __restrict__ f2N,
    float* __restrict__ ic)
{
    const int tid  = threadIdx.x;
    const int wv   = tid >> 6;
    const int lane = tid & 63;
    const int quad = lane >> 4;
    const int l15  = lane & 15;

    const int strip = blockIdx.x * 4 + wv;    // 0..8191
    const int b   = strip >> 11;
    const int rem = strip & 2047;
    const int h   = rem >> 4;
    const int x0  = (rem & 15) << 4;

    const size_t rowbase = (size_t)b * HW + (size_t)h * WIDTH;

    const unsigned short* arow = f1N + (rowbase + x0 + l15) * 128;
    s16x8 af[4];
    #pragma unroll
    for (int kk = 0; kk < 4; ++kk)
        af[kk] = *(const s16x8*)(arow + kk * 32 + quad * 8);

    f32x4 acc[4];
    #pragma unroll
    for (int nt = 0; nt < 4; ++nt) acc[nt] = (f32x4){0.f,0.f,0.f,0.f};

    #pragma unroll
    for (int nt = 0; nt < 4; ++nt){
        const int s = x0 + nt * 16 + l15 - 24;
        const bool valid = (s >= 0) && (s < WIDTH);
        const unsigned short* brow = f2N + (rowbase + s) * 128;
        #pragma unroll
        for (int kk = 0; kk < 4; ++kk){
            s16x8 bf = (s16x8){0,0,0,0,0,0,0,0};
            if (valid) bf = *(const s16x8*)(brow + kk * 32 + quad * 8);
            acc[nt] = __builtin_amdgcn_mfma_f32_16x16x32_bf16(af[kk], bf, acc[nt], 0, 0, 0);
        }
    }

    __shared__ float G[4][16][68];
    #pragma unroll
    for (int nt = 0; nt < 4; ++nt)
        #pragma unroll
        for (int r = 0; r < 4; ++r)
            G[wv][quad * 4 + r][nt * 16 + l15] = acc[nt][r];
    __syncthreads();

    float* obase = ic + (size_t)b * 49 * HW + (size_t)h * WIDTH + x0;
    #pragma unroll
    for (int i = 0; i < 13; ++i){
        int dd = quad + i * 4;
        if (dd < 49){
            float v = G[wv][l15][l15 + 48 - dd];
            obase[(size_t)dd * HW + l15] = v;
        }
    }
}

// ---------------------------------------------------------------------------
// K3: collapse geo path: M[s][i][k] = sum_o W_sel[s][i*96+o]*W_geo[o][k];
//     c0[s] = b_sel[s] + sum_{i,o} W_sel[s][i*96+o]*b_geo[o]
// ---------------------------------------------------------------------------
__global__ void k_prep(const float* __restrict__ Wsel, const float* __restrict__ bsel,
                       const float* __restrict__ Wgeo, const float* __restrict__ bgeo,
                       float* __restrict__ M, float* __restrict__ c0)
{
    int u = threadIdx.x;
    if (u < 441){
        int s = u / 147; int r = u % 147; int i = r / 49; int k = r % 49;
        float acc = 0.f;
        for (int o = 0; o < 96; ++o)
            acc += Wsel[s * 288 + i * 96 + o] * Wgeo[o * 49 + k];
        M[u] = acc;
    } else if (u < 444){
        int s = u - 441;
        float acc = bsel[s];
        for (int i = 0; i < 3; ++i)
            for (int o = 0; o < 96; ++o)
                acc += Wsel[s * 288 + i * 96 + o] * bgeo[o];
        c0[s] = acc;
    }
}

// ---------------------------------------------------------------------------
// K4: logits via collapsed M, softmax -> w, final = ic + w·cv.
// Single pass over cv: the 49x3 values are register-cached (full unroll),
// halving cv traffic vs the two-pass version.
// ---------------------------------------------------------------------------
__global__ __launch_bounds__(256, 2) void k_sel(
    const float* __restrict__ cv0, const float* __restrict__ cv1, const float* __restrict__ cv2,
    const float* __restrict__ M, const float* __restrict__ c0,
    const float* __restrict__ ic,
    float* __restrict__ finalO, float* __restrict__ wO)
{
    __shared__ float Ms[441];
    __shared__ float c0s[3];
    const int tid = threadIdx.x;
    for (int i = tid; i < 441; i += 256) Ms[i] = M[i];
    if (tid < 3) c0s[tid] = c0[tid];
    __syncthreads();

    const int gid = blockIdx.x * 256 + tid;   // 0..131071
    const int b = gid >> 15;
    const int p = gid & 32767;
    const size_t base = (size_t)b * 49 * HW + p;

    float a0[49], a1[49], a2[49];
    #pragma unroll
    for (int k = 0; k < 49; ++k){
        size_t o = base + (size_t)k * HW;
        a0[k] = cv0[o]; a1[k] = cv1[o]; a2[k] = cv2[o];
    }

    float lg0 = c0s[0], lg1 = c0s[1], lg2 = c0s[2];
    #pragma unroll
    for (int k = 0; k < 49; ++k){
        lg0 += Ms[k]       * a0[k] + Ms[49  + k] * a1[k] + Ms[98  + k] * a2[k];
        lg1 += Ms[147 + k] * a0[k] + Ms[196 + k] * a1[k] + Ms[245 + k] * a2[k];
        lg2 += Ms[294 + k] * a0[k] + Ms[343 + k] * a1[k] + Ms[392 + k] * a2[k];
    }
    float mx = fmaxf(lg0, fmaxf(lg1, lg2));
    float e0 = expf(lg0 - mx), e1 = expf(lg1 - mx), e2 = expf(lg2 - mx);
    float inv = 1.f / (e0 + e1 + e2);
    float w0 = e0 * inv, w1 = e1 * inv, w2 = e2 * inv;

    const size_t wbase = (size_t)b * 3 * HW + p;
    wO[wbase]          = w0;
    wO[wbase + HW]     = w1;
    wO[wbase + 2 * HW] = w2;

    #pragma unroll
    for (int k = 0; k < 49; ++k){
        size_t o = base + (size_t)k * HW;
        finalO[o] = ic[o] + w0 * a0[k] + w1 * a1[k] + w2 * a2[k];
    }
}

// ---------------------------------------------------------------------------
extern "C" void kernel_launch(void* const* d_in, const int* in_sizes, int n_in,
                              void* d_out, int out_size, void* d_ws, size_t ws_size,
                              hipStream_t stream)
{
    const float* feat_l1 = (const float*)d_in[0];
    const float* feat_r1 = (const float*)d_in[1];
    const float* cv0     = (const float*)d_in[2];
    const float* cv1     = (const float*)d_in[3];
    const float* cv2     = (const float*)d_in[4];
    const float* W_f1    = (const float*)d_in[5];
    const float* b_f1    = (const float*)d_in[6];
    const float* W_f2    = (const float*)d_in[7];
    const float* b_f2    = (const float*)d_in[8];
    const float* W_geo   = (const float*)d_in[9];
    const float* b_geo   = (const float*)d_in[10];
    const float* W_sel   = (const float*)d_in[11];
    const float* b_sel   = (const float*)d_in[12];

    float* finalO = (float*)d_out;
    float* icO    = (float*)d_out + 6422528;    // 4*49*128*256
    float* wO     = (float*)d_out + 12845056;   // + another 6422528

    // workspace: two bf16 normalized fmaps (transposed) + tiny M/c0
    unsigned short* f1N = (unsigned short*)d_ws;
    unsigned short* f2N = (unsigned short*)((char*)d_ws + 33554432);
    float* Mbuf  = (float*)((char*)d_ws + 67108864);
    float* c0buf = Mbuf + 441;

    k_prep<<<1, 512, 0, stream>>>(W_sel, b_sel, W_geo, b_geo, Mbuf, c0buf);
    k_fmap<<<dim3(128, 4, 2), 256, 0, stream>>>(feat_l1, feat_r1, W_f1, W_f2, b_f1, b_f2, f1N, f2N);
    k_corr<<<2048, 256, 0, stream>>>(f1N, f2N, icO);
    k_sel<<<512, 256, 0, stream>>>(cv0, cv1, cv2, Mbuf, c0buf, icO, finalO, wO);
}

// Round 4
// 280.966 us; speedup vs baseline: 1.0927x; 1.0739x over previous
//
#include <hip/hip_runtime.h>

#define HW 32768      // H*W per batch = 128*256
#define WIDTH 256

typedef float f32x4 __attribute__((ext_vector_type(4)));
typedef short s16x8 __attribute__((ext_vector_type(8)));

__device__ __forceinline__ unsigned short f2bf(float f){
    unsigned int u = __float_as_uint(f);
    u += 0x7FFFu + ((u >> 16) & 1u);      // round-to-nearest-even
    return (unsigned short)(u >> 16);
}
__device__ __forceinline__ unsigned int pk2(float a, float b){
    return (unsigned int)f2bf(a) | ((unsigned int)f2bf(b) << 16);
}

// ---------------------------------------------------------------------------
// Fused: fmap1/fmap2 GEMM (128x256x128) + per-pixel L2-norm + correlation.
// One block per (b,h) image row (256 px). Norm scales commute with the dot:
// corr = s1[x]*s2[x-d]*<f1raw,f2raw>, so fmaps are packed bf16 UNSCALED;
// scales applied in the gather epilogue.
//  - W staged to LDS bf16 (pool bytes 0..33791), reloaded per fmap.
//  - f1 raw bf16 kept in registers (f1p[64]); corr A-frags built by shuffles.
//  - f2 raw bf16 in LDS (pool as [256][132]) after GEMM2 (aliases W region).
//  - G diag-gather buffer aliases pool after corr MFMAs.
//  - feat global loads software-pipelined one nt-tile ahead for MLP.
// ---------------------------------------------------------------------------
__global__ __launch_bounds__(256, 2) void k_fused(
    const float* __restrict__ fl, const float* __restrict__ fr,
    const float* __restrict__ W1, const float* __restrict__ W2,
    const float* __restrict__ b1, const float* __restrict__ b2,
    float* __restrict__ ic)
{
    __shared__ char pool[67584];           // W(33.8K) -> f2s(67.6K) -> G(67.6K)
    __shared__ float s1[256], s2[256];
    unsigned short* Wlds = (unsigned short*)pool;   // [128][132] bf16
    unsigned short* f2s  = (unsigned short*)pool;   // [256][132] bf16
    float* G             = (float*)pool;            // [4][4][16][66] f32

    const int blk  = blockIdx.x;           // 512 blocks = 4 b x 128 h
    const int b    = blk >> 7;
    const int h    = blk & 127;
    const int tid  = threadIdx.x;
    const int wv   = tid >> 6;
    const int lane = tid & 63;
    const int quad = lane >> 4;
    const int l15  = lane & 15;

    const float* feats[2] = { fl + (size_t)b * 128 * HW + h * WIDTH,
                              fr + (size_t)b * 128 * HW + h * WIDTH };
    const float* Wms[2]   = { W1, W2 };
    const float* bss[2]   = { b1, b2 };

    unsigned int f1p[64];                  // f1 raw bf16 pairs (reg-resident)

    #pragma unroll 1
    for (int F = 0; F < 2; ++F){
        const float* featB = feats[F];
        const float* Wm    = Wms[F];
        const float* bias  = bss[F];

        __syncthreads();                   // prior pool readers done
        // stage W -> bf16 LDS [128][132] (row pad -> 2-way-free frag reads)
        {
            const int r = tid >> 1, c0 = (tid & 1) * 64;
            #pragma unroll
            for (int i = 0; i < 16; ++i){
                f32x4 v = *(const f32x4*)(Wm + r * 128 + c0 + i * 4);
                uint2 p; p.x = pk2(v[0], v[1]); p.y = pk2(v[2], v[3]);
                *(uint2*)&Wlds[r * 132 + c0 + i * 4] = p;
            }
        }
        __syncthreads();

        f32x4 acc[8][4];
        #pragma unroll
        for (int m = 0; m < 8; ++m)
            #pragma unroll
            for (int nt = 0; nt < 4; ++nt)
                acc[m][nt] = (f32x4){0.f, 0.f, 0.f, 0.f};

        float cur[8], nxt[8];
        {   // preload (kk=0, nt=0)
            const float* bp = featB + (size_t)(quad * 8) * HW + wv * 64 + l15;
            #pragma unroll
            for (int j = 0; j < 8; ++j) cur[j] = bp[(size_t)j * HW];
        }

        #pragma unroll
        for (int kk = 0; kk < 4; ++kk){
            s16x8 af[8];
            #pragma unroll
            for (int m = 0; m < 8; ++m){
                const int base = (m * 16 + l15) * 132 + kk * 32 + quad * 8;
                union { uint2 q2[2]; s16x8 v; } r;
                r.q2[0] = *(const uint2*)&Wlds[base];
                r.q2[1] = *(const uint2*)&Wlds[base + 4];
                af[m] = r.v;
            }
            #pragma unroll
            for (int nt = 0; nt < 4; ++nt){
                const int kn  = kk + ((nt + 1) >> 2);
                const int ntn = (nt + 1) & 3;
                if (kn < 4){               // issue next tile's loads early
                    const float* bp = featB + (size_t)(kn * 32 + quad * 8) * HW
                                      + wv * 64 + ntn * 16 + l15;
                    #pragma unroll
                    for (int j = 0; j < 8; ++j) nxt[j] = bp[(size_t)j * HW];
                }
                union { unsigned int u[4]; s16x8 v; } rb;
                rb.u[0] = pk2(cur[0], cur[1]); rb.u[1] = pk2(cur[2], cur[3]);
                rb.u[2] = pk2(cur[4], cur[5]); rb.u[3] = pk2(cur[6], cur[7]);
                #pragma unroll
                for (int m = 0; m < 8; ++m)
                    acc[m][nt] = __builtin_amdgcn_mfma_f32_16x16x32_bf16(af[m], rb.v, acc[m][nt], 0, 0, 0);
                #pragma unroll
                for (int j = 0; j < 8; ++j) cur[j] = nxt[j];
            }
        }

        // bias + inverse-norm per pixel
        float inv[4];
        #pragma unroll
        for (int nt = 0; nt < 4; ++nt){
            #pragma unroll
            for (int m = 0; m < 8; ++m)
                acc[m][nt] += *(const f32x4*)(bias + m * 16 + quad * 4);
            float n2 = 0.f;
            #pragma unroll
            for (int m = 0; m < 8; ++m)
                #pragma unroll
                for (int r = 0; r < 4; ++r)
                    n2 += acc[m][nt][r] * acc[m][nt][r];
            n2 += __shfl_xor(n2, 16, 64);
            n2 += __shfl_xor(n2, 32, 64);
            inv[nt] = 1.f / (sqrtf(n2) + 1e-8f);
        }

        if (F == 0){
            #pragma unroll
            for (int m = 0; m < 8; ++m)
                #pragma unroll
                for (int nt = 0; nt < 4; ++nt){
                    f1p[m * 8 + nt * 2 + 0] = pk2(acc[m][nt][0], acc[m][nt][1]);
                    f1p[m * 8 + nt * 2 + 1] = pk2(acc[m][nt][2], acc[m][nt][3]);
                }
            if (quad == 0){
                #pragma unroll
                for (int nt = 0; nt < 4; ++nt) s1[wv * 64 + nt * 16 + l15] = inv[nt];
            }
        } else {
            if (quad == 0){
                #pragma unroll
                for (int nt = 0; nt < 4; ++nt) s2[wv * 64 + nt * 16 + l15] = inv[nt];
            }
            __syncthreads();               // all W2 reads done; f2s overwrites pool
            #pragma unroll
            for (int nt = 0; nt < 4; ++nt){
                const int px = wv * 64 + nt * 16 + l15;
                #pragma unroll
                for (int m = 0; m < 8; ++m){
                    uint2 p;
                    p.x = pk2(acc[m][nt][0], acc[m][nt][1]);
                    p.y = pk2(acc[m][nt][2], acc[m][nt][3]);
                    *(uint2*)&f2s[px * 132 + m * 16 + quad * 4] = p;
                }
            }
        }
    }
    __syncthreads();                       // f2s complete

    // ---- correlation: per wave 4 strips of 16 px; A from f1p shuffles ----
    f32x4 acc_c[4][4];
    #pragma unroll
    for (int st = 0; st < 4; ++st)
        #pragma unroll
        for (int ct = 0; ct < 4; ++ct)
            acc_c[st][ct] = (f32x4){0.f, 0.f, 0.f, 0.f};

    #pragma unroll
    for (int st = 0; st < 4; ++st){
        s16x8 afc[4];
        #pragma unroll
        for (int kk = 0; kk < 4; ++kk){
            union { unsigned int u[4]; s16x8 v; } r;
            #pragma unroll
            for (int j2 = 0; j2 < 4; ++j2){
                const int rp  = j2 & 1;
                const int qs  = (quad & 1) * 2 + (j2 >> 1);
                const int src = qs * 16 + l15;
                unsigned int a0 = (unsigned int)__shfl((int)f1p[(kk * 2 + 0) * 8 + st * 2 + rp], src, 64);
                unsigned int a1 = (unsigned int)__shfl((int)f1p[(kk * 2 + 1) * 8 + st * 2 + rp], src, 64);
                r.u[j2] = (quad >> 1) ? a1 : a0;
            }
            afc[kk] = r.v;
        }
        #pragma unroll
        for (int ct = 0; ct < 4; ++ct){
            const int s = wv * 64 + st * 16 + ct * 16 + l15 - 24;
            const bool valid = (s >= 0) && (s < WIDTH);
            const int sc = valid ? s : 0;
            #pragma unroll
            for (int kk = 0; kk < 4; ++kk){
                union { uint2 q2[2]; s16x8 v; } rb;
                rb.q2[0] = *(const uint2*)&f2s[sc * 132 + kk * 32 + quad * 8];
                rb.q2[1] = *(const uint2*)&f2s[sc * 132 + kk * 32 + quad * 8 + 4];
                s16x8 bf = rb.v;
                if (!valid) bf = (s16x8){0,0,0,0,0,0,0,0};
                acc_c[st][ct] = __builtin_amdgcn_mfma_f32_16x16x32_bf16(afc[kk], bf, acc_c[st][ct], 0, 0, 0);
            }
        }
    }
    __syncthreads();                       // f2s reads done; G overwrites pool
    #pragma unroll
    for (int st = 0; st < 4; ++st)
        #pragma unroll
        for (int ct = 0; ct < 4; ++ct)
            #pragma unroll
            for (int r = 0; r < 4; ++r)
                G[((wv * 4 + st) * 16 + quad * 4 + r) * 66 + ct * 16 + l15] = acc_c[st][ct][r];
    __syncthreads();

    // diagonal gather + deferred norm scales; coalesced-ish stores
    float* obase = ic + (size_t)b * 49 * HW + (size_t)h * WIDTH;
    #pragma unroll
    for (int st = 0; st < 4; ++st){
        const int gx = wv * 64 + st * 16;
        const float sc1 = s1[gx + l15];
        const float* Grow = &G[((wv * 4 + st) * 16 + l15) * 66];
        #pragma unroll
        for (int i = 0; i < 13; ++i){
            const int dd = quad + i * 4;
            if (dd < 49){
                int s2i = gx + l15 + 24 - dd;
                s2i = s2i < 0 ? 0 : (s2i > 255 ? 255 : s2i);   // OOB -> raw 0 anyway
                const float v = Grow[l15 + 48 - dd] * sc1 * s2[s2i];
                obase[(size_t)dd * HW + gx + l15] = v;
            }
        }
    }
}

// ---------------------------------------------------------------------------
// K3: collapse geo path: M[s][i][k] = sum_o W_sel[s][i*96+o]*W_geo[o][k];
//     c0[s] = b_sel[s] + sum_{i,o} W_sel[s][i*96+o]*b_geo[o]
// ---------------------------------------------------------------------------
__global__ void k_prep(const float* __restrict__ Wsel, const float* __restrict__ bsel,
                       const float* __restrict__ Wgeo, const float* __restrict__ bgeo,
                       float* __restrict__ M, float* __restrict__ c0)
{
    int u = threadIdx.x;
    if (u < 441){
        int s = u / 147; int r = u % 147; int i = r / 49; int k = r % 49;
        float acc = 0.f;
        for (int o = 0; o < 96; ++o)
            acc += Wsel[s * 288 + i * 96 + o] * Wgeo[o * 49 + k];
        M[u] = acc;
    } else if (u < 444){
        int s = u - 441;
        float acc = bsel[s];
        for (int i = 0; i < 3; ++i)
            for (int o = 0; o < 96; ++o)
                acc += Wsel[s * 288 + i * 96 + o] * bgeo[o];
        c0[s] = acc;
    }
}

// ---------------------------------------------------------------------------
// K4: logits via collapsed M, softmax -> w, final = ic + w·cv (single pass)
// ---------------------------------------------------------------------------
__global__ __launch_bounds__(256, 2) void k_sel(
    const float* __restrict__ cv0, const float* __restrict__ cv1, const float* __restrict__ cv2,
    const float* __restrict__ M, const float* __restrict__ c0,
    const float* __restrict__ ic,
    float* __restrict__ finalO, float* __restrict__ wO)
{
    __shared__ float Ms[441];
    __shared__ float c0s[3];
    const int tid = threadIdx.x;
    for (int i = tid; i < 441; i += 256) Ms[i] = M[i];
    if (tid < 3) c0s[tid] = c0[tid];
    __syncthreads();

    const int gid = blockIdx.x * 256 + tid;   // 0..131071
    const int b = gid >> 15;
    const int p = gid & 32767;
    const size_t base = (size_t)b * 49 * HW + p;

    float a0[49], a1[49], a2[49];
    #pragma unroll
    for (int k = 0; k < 49; ++k){
        size_t o = base + (size_t)k * HW;
        a0[k] = cv0[o]; a1[k] = cv1[o]; a2[k] = cv2[o];
    }

    float lg0 = c0s[0], lg1 = c0s[1], lg2 = c0s[2];
    #pragma unroll
    for (int k = 0; k < 49; ++k){
        lg0 += Ms[k]       * a0[k] + Ms[49  + k] * a1[k] + Ms[98  + k] * a2[k];
        lg1 += Ms[147 + k] * a0[k] + Ms[196 + k] * a1[k] + Ms[245 + k] * a2[k];
        lg2 += Ms[294 + k] * a0[k] + Ms[343 + k] * a1[k] + Ms[392 + k] * a2[k];
    }
    float mx = fmaxf(lg0, fmaxf(lg1, lg2));
    float e0 = expf(lg0 - mx), e1 = expf(lg1 - mx), e2 = expf(lg2 - mx);
    float inv = 1.f / (e0 + e1 + e2);
    float w0 = e0 * inv, w1 = e1 * inv, w2 = e2 * inv;

    const size_t wbase = (size_t)b * 3 * HW + p;
    wO[wbase]          = w0;
    wO[wbase + HW]     = w1;
    wO[wbase + 2 * HW] = w2;

    #pragma unroll
    for (int k = 0; k < 49; ++k){
        size_t o = base + (size_t)k * HW;
        finalO[o] = ic[o] + w0 * a0[k] + w1 * a1[k] + w2 * a2[k];
    }
}

// ---------------------------------------------------------------------------
extern "C" void kernel_launch(void* const* d_in, const int* in_sizes, int n_in,
                              void* d_out, int out_size, void* d_ws, size_t ws_size,
                              hipStream_t stream)
{
    const float* feat_l1 = (const float*)d_in[0];
    const float* feat_r1 = (const float*)d_in[1];
    const float* cv0     = (const float*)d_in[2];
    const float* cv1     = (const float*)d_in[3];
    const float* cv2     = (const float*)d_in[4];
    const float* W_f1    = (const float*)d_in[5];
    const float* b_f1    = (const float*)d_in[6];
    const float* W_f2    = (const float*)d_in[7];
    const float* b_f2    = (const float*)d_in[8];
    const float* W_geo   = (const float*)d_in[9];
    const float* b_geo   = (const float*)d_in[10];
    const float* W_sel   = (const float*)d_in[11];
    const float* b_sel   = (const float*)d_in[12];

    float* finalO = (float*)d_out;
    float* icO    = (float*)d_out + 6422528;    // 4*49*128*256
    float* wO     = (float*)d_out + 12845056;   // + another 6422528

    float* Mbuf  = (float*)d_ws;
    float* c0buf = Mbuf + 441;

    k_prep<<<1, 512, 0, stream>>>(W_sel, b_sel, W_geo, b_geo, Mbuf, c0buf);
    k_fused<<<512, 256, 0, stream>>>(feat_l1, feat_r1, W_f1, W_f2, b_f1, b_f2, icO);
    k_sel<<<512, 256, 0, stream>>>(cv0, cv1, cv2, Mbuf, c0buf, icO, finalO, wO);
}

// Round 5
// 276.057 us; speedup vs baseline: 1.1121x; 1.0178x over previous
//
#include <hip/hip_runtime.h>

#define HW 32768      // H*W per batch = 128*256
#define WIDTH 256

typedef float f32x4 __attribute__((ext_vector_type(4)));
typedef short s16x8 __attribute__((ext_vector_type(8)));

__device__ __forceinline__ unsigned short f2bf(float f){
    unsigned int u = __float_as_uint(f);
    u += 0x7FFFu + ((u >> 16) & 1u);      // round-to-nearest-even
    return (unsigned short)(u >> 16);
}
__device__ __forceinline__ unsigned int pk2(float a, float b){
    return (unsigned int)f2bf(a) | ((unsigned int)f2bf(b) << 16);
}

// ---------------------------------------------------------------------------
// k_wconv: pre-pack W1/W2 (fp32 [128][128]) into bf16 MFMA A-fragment layout:
//   pair index pi = ((((F*4+kk)*8+m)*4+quad)*16+l15)*4 + j2
//   covers W[F][m*16+l15][kk*32+quad*8+2*j2 .. +1]
// so k_fused reads af[m] as ONE coalesced 16-B load (L2-hot, no pack VALU).
// ---------------------------------------------------------------------------
__global__ void k_wconv(const float* __restrict__ W1, const float* __restrict__ W2,
                        unsigned int* __restrict__ Wb)
{
    const int pi = blockIdx.x * 256 + threadIdx.x;   // 0..16383
    const int j2   = pi & 3;
    const int l15  = (pi >> 2) & 15;
    const int quad = (pi >> 6) & 3;
    const int m    = (pi >> 8) & 7;
    const int kk   = (pi >> 11) & 3;
    const int F    = (pi >> 13) & 1;
    const float* Wm = F ? W2 : W1;
    const int row = m * 16 + l15;
    const int ch  = kk * 32 + quad * 8 + j2 * 2;
    Wb[pi] = pk2(Wm[row * 128 + ch], Wm[row * 128 + ch + 1]);
}

// ---------------------------------------------------------------------------
// Fused: fmap GEMMs + per-pixel L2-norm + correlation, one block per (b,h).
// Order: f2 GEMM -> f2s(LDS); f1 GEMM -> f1p(regs) -> corr. This keeps f1p's
// 64 regs from overlapping a live GEMM accumulator (R4 spilled ~40MB here).
// Feat loads pipelined 2 tiles deep; W-frags are single 16-B L2-hot loads.
// Norm scales commute with the dot: applied in the gather epilogue.
// ---------------------------------------------------------------------------
__global__ __launch_bounds__(256, 2) void k_fused(
    const float* __restrict__ fl, const float* __restrict__ fr,
    const unsigned int* __restrict__ Wbu,
    const float* __restrict__ b1, const float* __restrict__ b2,
    float* __restrict__ ic)
{
    __shared__ __align__(16) char pool[67584];      // f2s -> G (time-aliased)
    __shared__ float s1[256], s2[256];
    unsigned short* f2s = (unsigned short*)pool;    // [256 px][132] bf16
    float* G            = (float*)pool;             // [256 rows][66] f32

    const int blk  = blockIdx.x;          // 512 = 4 b x 128 h
    const int b    = blk >> 7;
    const int h    = blk & 127;
    const int tid  = threadIdx.x;
    const int wv   = tid >> 6;
    const int lane = tid & 63;
    const int quad = lane >> 4;
    const int l15  = lane & 15;

    const float* feats[2] = { fl + (size_t)b * 128 * HW + h * WIDTH,
                              fr + (size_t)b * 128 * HW + h * WIDTH };
    const float* bss[2]   = { b1, b2 };

    unsigned int f1p[64];                 // f1 raw bf16 pairs (live only after F=0 GEMM)

    #pragma unroll 1
    for (int Fi = 0; Fi < 2; ++Fi){
        const int F = 1 - Fi;             // f2 first, then f1
        const float* featB = feats[F];
        const float* bias  = bss[F];
        const unsigned int* WbF = Wbu + F * 8192;

        f32x4 acc[8][4];
        #pragma unroll
        for (int m = 0; m < 8; ++m)
            #pragma unroll
            for (int nt = 0; nt < 4; ++nt)
                acc[m][nt] = (f32x4){0.f, 0.f, 0.f, 0.f};

        float buf[3][8];
        // preload tiles 0,1  (tile t = kk*4+nt; px = wv*64 + nt*16 + l15)
        #pragma unroll
        for (int t = 0; t < 2; ++t){
            const float* bp = featB + (size_t)(quad * 8) * HW + wv * 64 + t * 16 + l15;
            #pragma unroll
            for (int j = 0; j < 8; ++j) buf[t][j] = bp[(size_t)j * HW];
        }

        #pragma unroll
        for (int kk = 0; kk < 4; ++kk){
            // A-frags: one 16-B coalesced load per m (pre-packed bf16, L2-hot)
            s16x8 af[8];
            #pragma unroll
            for (int m = 0; m < 8; ++m)
                af[m] = *(const s16x8*)&WbF[(((kk * 8 + m) * 4 + quad) * 16 + l15) * 4];

            #pragma unroll
            for (int nt = 0; nt < 4; ++nt){
                const int t = kk * 4 + nt;
                if (t + 2 < 16){          // issue tile t+2 (2-deep pipeline)
                    const int kk2 = (t + 2) >> 2, nt2 = (t + 2) & 3;
                    const float* bp = featB + (size_t)(kk2 * 32 + quad * 8) * HW
                                      + wv * 64 + nt2 * 16 + l15;
                    #pragma unroll
                    for (int j = 0; j < 8; ++j) buf[(t + 2) % 3][j] = bp[(size_t)j * HW];
                }
                const float* cur = buf[t % 3];
                union { unsigned int u[4]; s16x8 v; } rb;
                rb.u[0] = pk2(cur[0], cur[1]); rb.u[1] = pk2(cur[2], cur[3]);
                rb.u[2] = pk2(cur[4], cur[5]); rb.u[3] = pk2(cur[6], cur[7]);
                #pragma unroll
                for (int m = 0; m < 8; ++m)
                    acc[m][nt] = __builtin_amdgcn_mfma_f32_16x16x32_bf16(af[m], rb.v, acc[m][nt], 0, 0, 0);
            }
        }

        // bias + inverse-norm per pixel
        float inv[4];
        #pragma unroll
        for (int nt = 0; nt < 4; ++nt){
            #pragma unroll
            for (int m = 0; m < 8; ++m)
                acc[m][nt] += *(const f32x4*)(bias + m * 16 + quad * 4);
            float n2 = 0.f;
            #pragma unroll
            for (int m = 0; m < 8; ++m)
                #pragma unroll
                for (int r = 0; r < 4; ++r)
                    n2 += acc[m][nt][r] * acc[m][nt][r];
            n2 += __shfl_xor(n2, 16, 64);
            n2 += __shfl_xor(n2, 32, 64);
            inv[nt] = 1.f / (sqrtf(n2) + 1e-8f);
        }

        if (F == 1){                      // f2 -> LDS (raw bf16) + s2
            if (quad == 0){
                #pragma unroll
                for (int nt = 0; nt < 4; ++nt) s2[wv * 64 + nt * 16 + l15] = inv[nt];
            }
            #pragma unroll
            for (int nt = 0; nt < 4; ++nt){
                const int px = wv * 64 + nt * 16 + l15;
                #pragma unroll
                for (int m = 0; m < 8; ++m){
                    uint2 p;
                    p.x = pk2(acc[m][nt][0], acc[m][nt][1]);
                    p.y = pk2(acc[m][nt][2], acc[m][nt][3]);
                    *(uint2*)&f2s[px * 132 + m * 16 + quad * 4] = p;
                }
            }
        } else {                          // f1 -> registers (raw bf16) + s1
            #pragma unroll
            for (int m = 0; m < 8; ++m)
                #pragma unroll
                for (int nt = 0; nt < 4; ++nt){
                    f1p[m * 8 + nt * 2 + 0] = pk2(acc[m][nt][0], acc[m][nt][1]);
                    f1p[m * 8 + nt * 2 + 1] = pk2(acc[m][nt][2], acc[m][nt][3]);
                }
            if (quad == 0){
                #pragma unroll
                for (int nt = 0; nt < 4; ++nt) s1[wv * 64 + nt * 16 + l15] = inv[nt];
            }
        }
    }
    __syncthreads();                      // f2s complete

    // ---- correlation: per wave 4 strips of 16 px; A from f1p shuffles ----
    f32x4 acc_c[4][4];
    #pragma unroll
    for (int st = 0; st < 4; ++st)
        #pragma unroll
        for (int ct = 0; ct < 4; ++ct)
            acc_c[st][ct] = (f32x4){0.f, 0.f, 0.f, 0.f};

    #pragma unroll
    for (int st = 0; st < 4; ++st){
        s16x8 afc[4];
        #pragma unroll
        for (int kk = 0; kk < 4; ++kk){
            union { unsigned int u[4]; s16x8 v; } r;
            #pragma unroll
            for (int j2 = 0; j2 < 4; ++j2){
                const int rp  = j2 & 1;
                const int qs  = (quad & 1) * 2 + (j2 >> 1);
                const int src = qs * 16 + l15;
                unsigned int a0 = (unsigned int)__shfl((int)f1p[(kk * 2 + 0) * 8 + st * 2 + rp], src, 64);
                unsigned int a1 = (unsigned int)__shfl((int)f1p[(kk * 2 + 1) * 8 + st * 2 + rp], src, 64);
                r.u[j2] = (quad >> 1) ? a1 : a0;
            }
            afc[kk] = r.v;
        }
        #pragma unroll
        for (int ct = 0; ct < 4; ++ct){
            const int s = wv * 64 + st * 16 + ct * 16 + l15 - 24;
            const bool valid = (s >= 0) && (s < WIDTH);
            const int sc = valid ? s : 0;
            #pragma unroll
            for (int kk = 0; kk < 4; ++kk){
                union { uint2 q2[2]; s16x8 v; } rb;
                rb.q2[0] = *(const uint2*)&f2s[sc * 132 + kk * 32 + quad * 8];
                rb.q2[1] = *(const uint2*)&f2s[sc * 132 + kk * 32 + quad * 8 + 4];
                s16x8 bf = rb.v;
                if (!valid) bf = (s16x8){0,0,0,0,0,0,0,0};
                acc_c[st][ct] = __builtin_amdgcn_mfma_f32_16x16x32_bf16(afc[kk], bf, acc_c[st][ct], 0, 0, 0);
            }
        }
    }
    __syncthreads();                      // all f2s reads done; G overwrites pool
    #pragma unroll
    for (int st = 0; st < 4; ++st)
        #pragma unroll
        for (int ct = 0; ct < 4; ++ct)
            #pragma unroll
            for (int r = 0; r < 4; ++r)
                G[((wv * 4 + st) * 16 + quad * 4 + r) * 66 + ct * 16 + l15] = acc_c[st][ct][r];
    __syncthreads();

    // diagonal gather + deferred norm scales
    float* obase = ic + (size_t)b * 49 * HW + (size_t)h * WIDTH;
    #pragma unroll
    for (int st = 0; st < 4; ++st){
        const int gx = wv * 64 + st * 16;
        const float sc1 = s1[gx + l15];
        const float* Grow = &G[((wv * 4 + st) * 16 + l15) * 66];
        #pragma unroll
        for (int i = 0; i < 13; ++i){
            const int dd = quad + i * 4;
            if (dd < 49){
                int s2i = gx + l15 + 24 - dd;
                s2i = s2i < 0 ? 0 : (s2i > 255 ? 255 : s2i);   // OOB -> raw 0 anyway
                const float v = Grow[l15 + 48 - dd] * sc1 * s2[s2i];
                obase[(size_t)dd * HW + gx + l15] = v;
            }
        }
    }
}

// ---------------------------------------------------------------------------
// k_prep: collapse geo path: M[s][i][k] = sum_o W_sel[s][i*96+o]*W_geo[o][k];
//         c0[s] = b_sel[s] + sum_{i,o} W_sel[s][i*96+o]*b_geo[o]
// ---------------------------------------------------------------------------
__global__ void k_prep(const float* __restrict__ Wsel, const float* __restrict__ bsel,
                       const float* __restrict__ Wgeo, const float* __restrict__ bgeo,
                       float* __restrict__ M, float* __restrict__ c0)
{
    int u = threadIdx.x;
    if (u < 441){
        int s = u / 147; int r = u % 147; int i = r / 49; int k = r % 49;
        float acc = 0.f;
        for (int o = 0; o < 96; ++o)
            acc += Wsel[s * 288 + i * 96 + o] * Wgeo[o * 49 + k];
        M[u] = acc;
    } else if (u < 444){
        int s = u - 441;
        float acc = bsel[s];
        for (int i = 0; i < 3; ++i)
            for (int o = 0; o < 96; ++o)
                acc += Wsel[s * 288 + i * 96 + o] * bgeo[o];
        c0[s] = acc;
    }
}

// ---------------------------------------------------------------------------
// k_sel: logits via collapsed M, softmax -> w, final = ic + w·cv (single pass)
// ---------------------------------------------------------------------------
__global__ __launch_bounds__(256, 2) void k_sel(
    const float* __restrict__ cv0, const float* __restrict__ cv1, const float* __restrict__ cv2,
    const float* __restrict__ M, const float* __restrict__ c0,
    const float* __restrict__ ic,
    float* __restrict__ finalO, float* __restrict__ wO)
{
    __shared__ float Ms[441];
    __shared__ float c0s[3];
    const int tid = threadIdx.x;
    for (int i = tid; i < 441; i += 256) Ms[i] = M[i];
    if (tid < 3) c0s[tid] = c0[tid];
    __syncthreads();

    const int gid = blockIdx.x * 256 + tid;   // 0..131071
    const int b = gid >> 15;
    const int p = gid & 32767;
    const size_t base = (size_t)b * 49 * HW + p;

    float a0[49], a1[49], a2[49];
    #pragma unroll
    for (int k = 0; k < 49; ++k){
        size_t o = base + (size_t)k * HW;
        a0[k] = cv0[o]; a1[k] = cv1[o]; a2[k] = cv2[o];
    }

    float lg0 = c0s[0], lg1 = c0s[1], lg2 = c0s[2];
    #pragma unroll
    for (int k = 0; k < 49; ++k){
        lg0 += Ms[k]       * a0[k] + Ms[49  + k] * a1[k] + Ms[98  + k] * a2[k];
        lg1 += Ms[147 + k] * a0[k] + Ms[196 + k] * a1[k] + Ms[245 + k] * a2[k];
        lg2 += Ms[294 + k] * a0[k] + Ms[343 + k] * a1[k] + Ms[392 + k] * a2[k];
    }
    float mx = fmaxf(lg0, fmaxf(lg1, lg2));
    float e0 = expf(lg0 - mx), e1 = expf(lg1 - mx), e2 = expf(lg2 - mx);
    float inv = 1.f / (e0 + e1 + e2);
    float w0 = e0 * inv, w1 = e1 * inv, w2 = e2 * inv;

    const size_t wbase = (size_t)b * 3 * HW + p;
    wO[wbase]          = w0;
    wO[wbase + HW]     = w1;
    wO[wbase + 2 * HW] = w2;

    #pragma unroll
    for (int k = 0; k < 49; ++k){
        size_t o = base + (size_t)k * HW;
        finalO[o] = ic[o] + w0 * a0[k] + w1 * a1[k] + w2 * a2[k];
    }
}

// ---------------------------------------------------------------------------
extern "C" void kernel_launch(void* const* d_in, const int* in_sizes, int n_in,
                              void* d_out, int out_size, void* d_ws, size_t ws_size,
                              hipStream_t stream)
{
    const float* feat_l1 = (const float*)d_in[0];
    const float* feat_r1 = (const float*)d_in[1];
    const float* cv0     = (const float*)d_in[2];
    const float* cv1     = (const float*)d_in[3];
    const float* cv2     = (const float*)d_in[4];
    const float* W_f1    = (const float*)d_in[5];
    const float* b_f1    = (const float*)d_in[6];
    const float* W_f2    = (const float*)d_in[7];
    const float* b_f2    = (const float*)d_in[8];
    const float* W_geo   = (const float*)d_in[9];
    const float* b_geo   = (const float*)d_in[10];
    const float* W_sel   = (const float*)d_in[11];
    const float* b_sel   = (const float*)d_in[12];

    float* finalO = (float*)d_out;
    float* icO    = (float*)d_out + 6422528;    // 4*49*128*256
    float* wO     = (float*)d_out + 12845056;   // + another 6422528

    unsigned int* Wb = (unsigned int*)d_ws;     // 16384 uints = 64 KB
    float* Mbuf  = (float*)((char*)d_ws + 65536);
    float* c0buf = Mbuf + 441;

    k_wconv<<<64, 256, 0, stream>>>(W_f1, W_f2, Wb);
    k_prep<<<1, 512, 0, stream>>>(W_sel, b_sel, W_geo, b_geo, Mbuf, c0buf);
    k_fused<<<512, 256, 0, stream>>>(feat_l1, feat_r1, Wb, b_f1, b_f2, icO);
    k_sel<<<512, 256, 0, stream>>>(cv0, cv1, cv2, Mbuf, c0buf, icO, finalO, wO);
}